// Round 11
// baseline (164.205 us; speedup 1.0000x reference)
//
#include <hip/hip_runtime.h>
#include <hip/hip_bf16.h>

// PriorScaleShift:
//   x:         (B=1024, S=512) int32 token ids in [0, 32000)
//   mask:      (B, S, 1) float32  (nonnegative, uniform [0,1))
//   log_scale: (1, 1, V=32000) float32
//   shift:     (1, 1, V) float32
//   out:       (B, 1, V) float32 = exp(log_scale)*presence + shift
// presence[b,v] = 1 iff exists s: x[b,s]==v and mask[b,s] > 0.
//
// Round 8 insight: <=512 of 32000 vocab entries per row are present, so
// >=98.4% of out is exactly shift[v]. Structure (single kernel, no LDS,
// no tables):
//   phase 1: stream shift chunk -> out row chunk (1 load + 1 store per 16B;
//            the 131 MB write path carries ~no VALU work)
//   barrier  (__syncthreads drains vmcnt(0) -> stream stores visible in L2)
//   phase 2: for row tokens in this chunk with mask>0:
//            out[row,v] = expf(ls[v]) + sh[v]   (~512K scattered 4B stores
//            chip-wide, hitting lines this block just wrote -> L2 merge)
// Benign races: duplicate (row,v) fixups write identical values.

#define PSS_VOCAB  32000
#define PSS_SEQ    512
#define PSS_BLOCK  256
#define PSS_CHUNKS 4
#define PSS_CHUNK  (PSS_VOCAB / PSS_CHUNKS)   // 8000 floats
#define PSS_CF4    (PSS_CHUNK / 4)            // 2000 float4 per chunk

typedef float v4f __attribute__((ext_vector_type(4)));

__global__ __launch_bounds__(PSS_BLOCK)
void PriorScaleShift_47467978556092_kernel(const int* __restrict__ x,
                                           const float* __restrict__ mask,
                                           const float* __restrict__ log_scale,
                                           const float* __restrict__ shift,
                                           float* __restrict__ out) {
    const int bid   = blockIdx.x;
    const int row   = bid >> 2;                 // bid / PSS_CHUNKS
    const int c     = bid & (PSS_CHUNKS - 1);
    const int t     = threadIdx.x;
    const int vbase = c * PSS_CHUNK;

    float* orow = out + (size_t)row * PSS_VOCAB;

    // Phase 1: broadcast-stream shift into this row chunk.
    {
        const v4f* s4 = (const v4f*)(shift + vbase);
        v4f*       o4 = (v4f*)(orow + vbase);
        #pragma unroll 2
        for (int i = t; i < PSS_CF4; i += PSS_BLOCK)
            o4[i] = s4[i];
    }

    __syncthreads();   // vmcnt(0) drain: stream stores precede fixups in L2

    // Phase 2: sparse fixups for tokens present in this row & chunk.
    {
        const int*   xr = x    + (size_t)row * PSS_SEQ;
        const float* mr = mask + (size_t)row * PSS_SEQ;
        #pragma unroll
        for (int s = t; s < PSS_SEQ; s += PSS_BLOCK) {
            const int      v   = xr[s];
            const unsigned rel = (unsigned)(v - vbase);
            if (rel < (unsigned)PSS_CHUNK && mr[s] > 0.0f)
                orow[v] = expf(log_scale[v]) + shift[v];
        }
    }
}

extern "C" void kernel_launch(void* const* d_in, const int* in_sizes, int n_in,
                              void* d_out, int out_size, void* d_ws, size_t ws_size,
                              hipStream_t stream) {
    const int*   x         = (const int*)d_in[0];
    const float* mask      = (const float*)d_in[1];
    const float* log_scale = (const float*)d_in[2];
    const float* shift     = (const float*)d_in[3];
    float* out = (float*)d_out;

    const int batch = in_sizes[0] / PSS_SEQ;   // 1024

    PriorScaleShift_47467978556092_kernel<<<batch * PSS_CHUNKS, PSS_BLOCK, 0, stream>>>(
        x, mask, log_scale, shift, out);
}